// Round 1
// 408.024 us; speedup vs baseline: 1.0047x; 1.0047x over previous
//
#include <hip/hip_runtime.h>
#include <hip/hip_bf16.h>
#include <cmath>

typedef __bf16 bf16;
typedef __bf16 bf16x4 __attribute__((ext_vector_type(4)));
typedef __bf16 bf16x8 __attribute__((ext_vector_type(8)));
typedef float f32x4 __attribute__((ext_vector_type(4)));

#define BB 2
#define SS 2048
#define DD 1024
#define HH 16
#define WW 16
#define HDD 64
#define DFFD 4096
#define NTOK (BB*SS)

__device__ __forceinline__ float gelu_f(float x) {
    const float c = 0.7978845608028654f;  // sqrt(2/pi)
    float t = tanhf(c * (x + 0.044715f * x * x * x));
    return 0.5f * x * (1.0f + t);
}

// ---- async global->LDS 16B/lane. LDS dest = wave-uniform base + lane*16 (m104/m108). ----
__device__ __forceinline__ void glds16(const bf16* g, const bf16* l) {
    __builtin_amdgcn_global_load_lds(
        (const __attribute__((address_space(1))) void*)(uintptr_t)(const void*)g,
        (__attribute__((address_space(3))) void*)(unsigned)(uintptr_t)(const void*)l,
        16, 0, 0);
}

// ---------------- fp32 -> bf16 convert, 8 elems/thread ----------------
__global__ __launch_bounds__(256) void conv_kernel(
    const float* __restrict__ src, bf16* __restrict__ dst, int n8)
{
    int i = blockIdx.x * 256 + threadIdx.x;
    if (i >= n8) return;
    f32x4 a = *(const f32x4*)(src + (size_t)i * 8);
    f32x4 b = *(const f32x4*)(src + (size_t)i * 8 + 4);
    bf16x8 v;
#pragma unroll
    for (int j = 0; j < 4; j++) { v[j] = (bf16)a[j]; v[4 + j] = (bf16)b[j]; }
    *(bf16x8*)(dst + (size_t)i * 8) = v;
}

// ---------------- fused LayerNorm: fp32 row -> bf16 row, one block/row ----------------
__global__ __launch_bounds__(256) void ln_kernel(
    const float* __restrict__ x, const float* __restrict__ g, const float* __restrict__ b,
    bf16* __restrict__ out)
{
    const int row = blockIdx.x, t = threadIdx.x;
    f32x4 v = *(const f32x4*)(x + (size_t)row * DD + t * 4);
    float s  = v[0] + v[1] + v[2] + v[3];
    float s2 = v[0]*v[0] + v[1]*v[1] + v[2]*v[2] + v[3]*v[3];
#pragma unroll
    for (int off = 32; off >= 1; off >>= 1) {
        s  += __shfl_xor(s,  off, 64);
        s2 += __shfl_xor(s2, off, 64);
    }
    __shared__ float red[8];
    const int wave = t >> 6;
    if ((t & 63) == 0) { red[wave] = s; red[4 + wave] = s2; }
    __syncthreads();
    float ts  = red[0] + red[1] + red[2] + red[3];
    float ts2 = red[4] + red[5] + red[6] + red[7];
    float mean = ts * (1.0f / DD);
    float var  = ts2 * (1.0f / DD) - mean * mean;
    float rstd = rsqrtf(var + 1e-5f);
    f32x4 gv = *(const f32x4*)(g + t * 4);
    f32x4 bv = *(const f32x4*)(b + t * 4);
    bf16x4 o;
#pragma unroll
    for (int i = 0; i < 4; i++) o[i] = (bf16)((v[i] - mean) * rstd * gv[i] + bv[i]);
    *(bf16x4*)(out + (size_t)row * DD + t * 4) = o;
}

// ---------------- bf16 MFMA GEMM w/ global_load_lds: C[M,N] = A[M,K] @ W[N,K]^T + bias ----
// TM: 128 (waves 2x2, 4x4 frags) or 64 (waves 1x4, 4x2 frags). BN=128, BK=32, 256 thr.
// ACT: 1=gelu. RESID: 2=add fp32 resid (may alias fp32 Cout: same elem, same thread,
// read-before-write). RESID=3: split-K over gridDim.z — each z-block computes its
// K-slice partial and unsafeAtomicAdd's it into fp32 Cout (Cout must be pre-primed
// with the residual); bias added by z==0 only. OUTF32: 1=fp32 out, 0=bf16.
template<int TM, int ACT, int RESID, int OUTF32>
__global__ __launch_bounds__(256) void gemm_glds(
    const bf16* __restrict__ A, const bf16* __restrict__ Bw,
    const float* __restrict__ bias,
    const float* resid, void* __restrict__ Cout, int N, int K)
{
    constexpr int MI = 4;
    constexpr int NJ = (TM == 128) ? 4 : 2;
    __shared__ __align__(16) bf16 As[TM * 32];
    __shared__ __align__(16) bf16 Bs[128 * 32];
    const int t = threadIdx.x;
    const int m0 = blockIdx.y * TM, n0 = blockIdx.x * 128;
    const int lane = t & 63, w = t >> 6;
    const int wm = (TM == 128) ? (w & 1) * 64 : 0;
    const int wn = (TM == 128) ? (w >> 1) * 64 : w * 32;
    const int quad = lane >> 4, l16 = lane & 15;
    const int srow = t >> 2, scol = (t & 3) * 8;   // 4 lanes/row, 8 bf16 (16 B) each

    const bf16* Ag = A  + (size_t)(m0 + srow) * K + scol;
    const bf16* Bg = Bw + (size_t)(n0 + srow) * K + scol;
    const bf16* AsW = As + w * 512;   // wave-uniform LDS base (+i*2048 per 64-row chunk)
    const bf16* BsW = Bs + w * 512;

    int k_lo = 0, k_hi = K;
    if (RESID == 3) {                 // split-K: this block handles one K-slice
        const int ks = K / gridDim.z;
        k_lo = blockIdx.z * ks;
        k_hi = k_lo + ks;
    }

    const f32x4 zero = {0.f, 0.f, 0.f, 0.f};
    f32x4 acc[MI][NJ];
#pragma unroll
    for (int i = 0; i < MI; i++)
#pragma unroll
        for (int j = 0; j < NJ; j++) acc[i][j] = zero;

    for (int k0 = k_lo; k0 < k_hi; k0 += 32) {
        __syncthreads();                       // all waves done reading previous tile
        glds16(Ag + k0, AsW);
        if (TM == 128) glds16(Ag + (size_t)64 * K + k0, AsW + 2048);
        glds16(Bg + k0, BsW);
        glds16(Bg + (size_t)64 * K + k0, BsW + 2048);
        __syncthreads();                       // drains vmcnt -> LDS tiles visible
        bf16x8 af[MI], bfr[NJ];
#pragma unroll
        for (int i = 0; i < MI; i++)
            af[i] = *(const bf16x8*)(As + (wm + i * 16 + l16) * 32 + quad * 8);
#pragma unroll
        for (int j = 0; j < NJ; j++)
            bfr[j] = *(const bf16x8*)(Bs + (wn + j * 16 + l16) * 32 + quad * 8);
#pragma unroll
        for (int i = 0; i < MI; i++)
#pragma unroll
            for (int j = 0; j < NJ; j++)
                acc[i][j] = __builtin_amdgcn_mfma_f32_16x16x32_bf16(af[i], bfr[j], acc[i][j], 0, 0, 0);
    }

#pragma unroll
    for (int i = 0; i < MI; i++) {
#pragma unroll
        for (int j = 0; j < NJ; j++) {
            int col = n0 + wn + j * 16 + l16;
            float bv = bias[col];
            if (RESID == 3 && blockIdx.z != 0) bv = 0.0f;
#pragma unroll
            for (int r = 0; r < 4; r++) {
                int row = m0 + wm + i * 16 + quad * 4 + r;
                float val = acc[i][j][r] + bv;
                if (ACT == 1) val = gelu_f(val);
                size_t idx = (size_t)row * N + col;
                if (RESID == 2) val += resid[idx];
                if (RESID == 3) {
                    unsafeAtomicAdd(&((float*)Cout)[idx], val);   // HW global_atomic_add_f32
                } else if (OUTF32) {
                    ((float*)Cout)[idx] = val;
                } else {
                    ((bf16*)Cout)[idx] = (bf16)val;
                }
            }
        }
    }
}

// ---------------- Sliding-window causal attention: one wave per (b,h,q) ----------------
__global__ __launch_bounds__(256) void attn_kernel(
    const bf16* __restrict__ qkv, bf16* __restrict__ o)
{
    const int gw = blockIdx.x * 4 + (threadIdx.x >> 6);
    const int lane = threadIdx.x & 63;
    const int q = gw & (SS - 1);
    const int h = (gw >> 11) & (HH - 1);
    const int b = gw >> 15;
    const size_t rowstride = 3 * DD;
    const bf16* base = qkv + (size_t)b * SS * rowstride + h * HDD + lane;
    float qd = (float)base[(size_t)q * rowstride] * 0.125f;  // 1/sqrt(64)
    float kv[WW], vv[WW];
#pragma unroll
    for (int j = 0; j < WW; j++) {
        int key = q - (WW - 1) + j;
        int kc = key < 0 ? 0 : key;
        const bf16* kp = base + (size_t)kc * rowstride + DD;
        kv[j] = (float)kp[0];
        vv[j] = (float)kp[DD];
    }
    float sc[WW];
#pragma unroll
    for (int j = 0; j < WW; j++) {
        float p = qd * kv[j];
        p += __shfl_xor(p, 32, 64);
        p += __shfl_xor(p, 16, 64);
        p += __shfl_xor(p,  8, 64);
        p += __shfl_xor(p,  4, 64);
        p += __shfl_xor(p,  2, 64);
        p += __shfl_xor(p,  1, 64);
        sc[j] = (q - (WW - 1) + j >= 0) ? p : -1e30f;
    }
    float m = sc[0];
#pragma unroll
    for (int j = 1; j < WW; j++) m = fmaxf(m, sc[j]);
    float l = 0.f, od = 0.f;
#pragma unroll
    for (int j = 0; j < WW; j++) {
        float e = __expf(sc[j] - m);
        l += e;
        od += e * vv[j];
    }
    o[(size_t)(b * SS + q) * DD + h * HDD + lane] = (bf16)(od / l);
}

// ---------------- launch ----------------
extern "C" void kernel_launch(void* const* d_in, const int* in_sizes, int n_in,
                              void* d_out, int out_size, void* d_ws, size_t ws_size,
                              hipStream_t stream)
{
    (void)in_sizes; (void)n_in; (void)out_size; (void)ws_size;
    const float* x    = (const float*)d_in[0];
    const float* ln1g = (const float*)d_in[1];
    const float* ln1b = (const float*)d_in[2];
    const float* Wqkv = (const float*)d_in[3];
    const float* bqkv = (const float*)d_in[4];
    const float* Wout = (const float*)d_in[5];
    const float* bout = (const float*)d_in[6];
    const float* ln2g = (const float*)d_in[7];
    const float* ln2b = (const float*)d_in[8];
    const float* W1   = (const float*)d_in[9];
    const float* b1   = (const float*)d_in[10];
    const float* W2   = (const float*)d_in[11];
    const float* b2   = (const float*)d_in[12];

    // Workspace (exactly 56 MiB peak; R2's 56 MiB layout proved ws >= 56 MiB):
    //   [0,16M)  W region. Phase A: Wqkv_bf @0..6M, Wout_bf @6..8M.
    //            Phase B: W1_bf @0..8M, W2_bf @8..16M (conv after out-proj).
    //   [16,48M) P region. Phase A: qkv bf16 24 MiB. Phase B: h1 bf16 32 MiB.
    //   [48,56M) H region: h (LN1 out) -> o (attn out) -> xn (LN2 out), serially.
    //   x1 fp32 lives in d_out; MLP2 split-K atomically accumulates in place
    //   (x1 already holds the residual written by the out-proj GEMM).
    const size_t MB = (size_t)1 << 20;
    char* ws = (char*)d_ws;
    bf16* wqkv_bf = (bf16*)(ws);
    bf16* wout_bf = (bf16*)(ws + 6 * MB);
    bf16* w1_bf   = (bf16*)(ws);
    bf16* w2_bf   = (bf16*)(ws + 8 * MB);
    bf16* qkv     = (bf16*)(ws + 16 * MB);
    bf16* h1      = (bf16*)(ws + 16 * MB);
    bf16* hbuf    = (bf16*)(ws + 48 * MB);   // h, then o, then xn
    float* x1     = (float*)d_out;

    const dim3 blk(256);

    // Phase A: weights for QKV + out-proj
    conv_kernel<<<(3 * DD * DD / 8) / 256, blk, 0, stream>>>(Wqkv, wqkv_bf, 3 * DD * DD / 8);
    conv_kernel<<<(DD * DD / 8) / 256, blk, 0, stream>>>(Wout, wout_bf, DD * DD / 8);
    // h = LN1(x)
    ln_kernel<<<NTOK, blk, 0, stream>>>(x, ln1g, ln1b, hbuf);
    // qkv = h @ Wqkv^T + bqkv           (M=4096, N=3072, K=1024)
    gemm_glds<128, 0, 0, 0><<<dim3(24, 32), blk, 0, stream>>>(
        hbuf, wqkv_bf, bqkv, nullptr, qkv, 3 * DD, DD);
    // o = attention(qkv)  (o overwrites h — h dead)
    attn_kernel<<<BB * HH * SS / 4, blk, 0, stream>>>(qkv, hbuf);
    // x1 = x + o @ Wout^T + bout        (fp32 into d_out; M=4096, N=1024, K=1024)
    gemm_glds<64, 0, 2, 1><<<dim3(8, 64), blk, 0, stream>>>(
        hbuf, wout_bf, bout, x, x1, DD, DD);

    // Phase B: weights for MLP (overwrites phase-A weights; stream-ordered after out-proj)
    conv_kernel<<<(DFFD * DD / 8) / 256, blk, 0, stream>>>(W1, w1_bf, DFFD * DD / 8);
    conv_kernel<<<(DFFD * DD / 8) / 256, blk, 0, stream>>>(W2, w2_bf, DFFD * DD / 8);
    // xn = LN2(x1)   (xn overwrites o — o dead)
    ln_kernel<<<NTOK, blk, 0, stream>>>(x1, ln2g, ln2b, hbuf);
    // h1 = gelu(xn @ W1^T + b1)         (M=4096, N=4096, K=1024; h1 overwrites qkv)
    gemm_glds<128, 1, 0, 0><<<dim3(32, 32), blk, 0, stream>>>(
        hbuf, w1_bf, b1, nullptr, h1, DFFD, DD);
    // out = x1 + h1 @ W2^T + b2         (split-K=2, TM=128: grid 512 blocks = 2/CU,
    //   16 MFMA/wave per barrier; atomics accumulate into pre-primed x1 in d_out)
    gemm_glds<128, 0, 3, 1><<<dim3(8, 32, 2), blk, 0, stream>>>(
        h1, w2_bf, b2, nullptr, x1, DD, DFFD);
}

// Round 2
// 369.504 us; speedup vs baseline: 1.1095x; 1.1042x over previous
//
#include <hip/hip_runtime.h>
#include <hip/hip_bf16.h>
#include <cmath>

typedef __bf16 bf16;
typedef __bf16 bf16x4 __attribute__((ext_vector_type(4)));
typedef __bf16 bf16x8 __attribute__((ext_vector_type(8)));
typedef float f32x4 __attribute__((ext_vector_type(4)));

#define BB 2
#define SS 2048
#define DD 1024
#define HH 16
#define WW 16
#define HDD 64
#define DFFD 4096
#define NTOK (BB*SS)

// gelu(x) = 0.5x(1+tanh(c(x+0.044715x^3))) = x*sigmoid(2c(x+0.044715x^3))
// sigmoid form: 1 v_exp_f32 instead of tanhf's ~30-op expansion.
__device__ __forceinline__ float gelu_f(float x) {
    const float k = 1.5957691216057308f;  // 2*sqrt(2/pi)
    float u = k * (x + 0.044715f * x * x * x);
    return x / (1.0f + __expf(-u));
}

// ---- async global->LDS 16B/lane. LDS dest = wave-uniform base + lane*16 (m104/m108). ----
__device__ __forceinline__ void glds16(const bf16* g, const bf16* l) {
    __builtin_amdgcn_global_load_lds(
        (const __attribute__((address_space(1))) void*)(uintptr_t)(const void*)g,
        (__attribute__((address_space(3))) void*)(unsigned)(uintptr_t)(const void*)l,
        16, 0, 0);
}

// ---------------- fp32 -> bf16 convert, 8 elems/thread ----------------
__global__ __launch_bounds__(256) void conv_kernel(
    const float* __restrict__ src, bf16* __restrict__ dst, int n8)
{
    int i = blockIdx.x * 256 + threadIdx.x;
    if (i >= n8) return;
    f32x4 a = *(const f32x4*)(src + (size_t)i * 8);
    f32x4 b = *(const f32x4*)(src + (size_t)i * 8 + 4);
    bf16x8 v;
#pragma unroll
    for (int j = 0; j < 4; j++) { v[j] = (bf16)a[j]; v[4 + j] = (bf16)b[j]; }
    *(bf16x8*)(dst + (size_t)i * 8) = v;
}

// ---------------- fused LayerNorm: fp32 row -> bf16 row, one block/row ----------------
__global__ __launch_bounds__(256) void ln_kernel(
    const float* __restrict__ x, const float* __restrict__ g, const float* __restrict__ b,
    bf16* __restrict__ out)
{
    const int row = blockIdx.x, t = threadIdx.x;
    f32x4 v = *(const f32x4*)(x + (size_t)row * DD + t * 4);
    float s  = v[0] + v[1] + v[2] + v[3];
    float s2 = v[0]*v[0] + v[1]*v[1] + v[2]*v[2] + v[3]*v[3];
#pragma unroll
    for (int off = 32; off >= 1; off >>= 1) {
        s  += __shfl_xor(s,  off, 64);
        s2 += __shfl_xor(s2, off, 64);
    }
    __shared__ float red[8];
    const int wave = t >> 6;
    if ((t & 63) == 0) { red[wave] = s; red[4 + wave] = s2; }
    __syncthreads();
    float ts  = red[0] + red[1] + red[2] + red[3];
    float ts2 = red[4] + red[5] + red[6] + red[7];
    float mean = ts * (1.0f / DD);
    float var  = ts2 * (1.0f / DD) - mean * mean;
    float rstd = rsqrtf(var + 1e-5f);
    f32x4 gv = *(const f32x4*)(g + t * 4);
    f32x4 bv = *(const f32x4*)(b + t * 4);
    bf16x4 o;
#pragma unroll
    for (int i = 0; i < 4; i++) o[i] = (bf16)((v[i] - mean) * rstd * gv[i] + bv[i]);
    *(bf16x4*)(out + (size_t)row * DD + t * 4) = o;
}

// ---------------- bf16 MFMA GEMM, 2-phase double-buffered glds prefetch ----------------
// C[M,N] = A[M,K] @ W[N,K]^T + bias.
// TM: 128 (waves 2x2, 4x4 frags) or 64 (waves 1x4, 4x2 frags). BN=128, BK=32, 256 thr.
// T3-minimum-2phase (learn_hip m228d: 622 TF @128^2): per k-step, issue NEXT tile's
// global_load_lds into buf[step^1], then ds_read+MFMA buf[step], then ONE
// __syncthreads (its implicit vmcnt(0)+lgkmcnt(0) drain is the buffer handoff).
// Load latency of tile t+1 hides under compute of tile t; 1 barrier/k-step.
// ACT: 1=gelu. RESID: 2=add fp32 resid (may alias fp32 Cout: same elem, same thread,
// read-before-write). RESID=3: split-K over gridDim.z, unsafeAtomicAdd partials into
// pre-primed fp32 Cout; bias added by z==0 only. OUTF32: 1=fp32 out, 0=bf16.
template<int TM, int ACT, int RESID, int OUTF32>
__global__ __launch_bounds__(256) void gemm_glds(
    const bf16* __restrict__ A, const bf16* __restrict__ Bw,
    const float* __restrict__ bias,
    const float* resid, void* __restrict__ Cout, int N, int K)
{
    constexpr int MI = 4;
    constexpr int NJ = (TM == 128) ? 4 : 2;
    __shared__ __align__(16) bf16 As[2 * TM * 32];
    __shared__ __align__(16) bf16 Bs[2 * 128 * 32];
    const int t = threadIdx.x;
    const int m0 = blockIdx.y * TM, n0 = blockIdx.x * 128;
    const int lane = t & 63, w = t >> 6;
    const int wm = (TM == 128) ? (w & 1) * 64 : 0;
    const int wn = (TM == 128) ? (w >> 1) * 64 : w * 32;
    const int quad = lane >> 4, l16 = lane & 15;
    const int srow = t >> 2, scol = (t & 3) * 8;   // 4 lanes/row, 8 bf16 (16 B) each

    const bf16* Ag = A  + (size_t)(m0 + srow) * K + scol;
    const bf16* Bg = Bw + (size_t)(n0 + srow) * K + scol;

    int k_lo = 0, k_hi = K;
    if (RESID == 3) {                 // split-K: this block handles one K-slice
        const int ks = K / gridDim.z;
        k_lo = blockIdx.z * ks;
        k_hi = k_lo + ks;
    }

    // stage tile at k0 into LDS buffer `buf` (per-wave-owned linear regions)
    auto stage = [&](int buf, int k0) {
        const bf16* AsW = As + buf * (TM * 32) + w * 512;
        const bf16* BsW = Bs + buf * (128 * 32) + w * 512;
        glds16(Ag + k0, AsW);
        if (TM == 128) glds16(Ag + (size_t)64 * K + k0, AsW + 2048);
        glds16(Bg + k0, BsW);
        glds16(Bg + (size_t)64 * K + k0, BsW + 2048);
    };

    const f32x4 zero = {0.f, 0.f, 0.f, 0.f};
    f32x4 acc[MI][NJ];
#pragma unroll
    for (int i = 0; i < MI; i++)
#pragma unroll
        for (int j = 0; j < NJ; j++) acc[i][j] = zero;

    const int nsteps = (k_hi - k_lo) >> 5;
    stage(0, k_lo);
    __syncthreads();                           // drains vmcnt -> buf0 visible

    for (int step = 0; step < nsteps; ++step) {
        const int cur = step & 1;
        if (step + 1 < nsteps)
            stage(cur ^ 1, k_lo + ((step + 1) << 5));   // prefetch next tile
        const bf16* Ab = As + cur * (TM * 32);
        const bf16* Bb = Bs + cur * (128 * 32);
        bf16x8 af[MI], bfr[NJ];
#pragma unroll
        for (int i = 0; i < MI; i++)
            af[i] = *(const bf16x8*)(Ab + (wm + i * 16 + l16) * 32 + quad * 8);
#pragma unroll
        for (int j = 0; j < NJ; j++)
            bfr[j] = *(const bf16x8*)(Bb + (wn + j * 16 + l16) * 32 + quad * 8);
#pragma unroll
        for (int i = 0; i < MI; i++)
#pragma unroll
            for (int j = 0; j < NJ; j++)
                acc[i][j] = __builtin_amdgcn_mfma_f32_16x16x32_bf16(af[i], bfr[j], acc[i][j], 0, 0, 0);
        __syncthreads();   // implicit vmcnt(0)+lgkmcnt(0): prefetch landed, reads done
    }

#pragma unroll
    for (int i = 0; i < MI; i++) {
#pragma unroll
        for (int j = 0; j < NJ; j++) {
            int col = n0 + wn + j * 16 + l16;
            float bv = bias[col];
            if (RESID == 3 && blockIdx.z != 0) bv = 0.0f;
#pragma unroll
            for (int r = 0; r < 4; r++) {
                int row = m0 + wm + i * 16 + quad * 4 + r;
                float val = acc[i][j][r] + bv;
                if (ACT == 1) val = gelu_f(val);
                size_t idx = (size_t)row * N + col;
                if (RESID == 2) val += resid[idx];
                if (RESID == 3) {
                    unsafeAtomicAdd(&((float*)Cout)[idx], val);   // HW global_atomic_add_f32
                } else if (OUTF32) {
                    ((float*)Cout)[idx] = val;
                } else {
                    ((bf16*)Cout)[idx] = (bf16)val;
                }
            }
        }
    }
}

// ---------------- Sliding-window causal attention: one wave per (b,h,q) ----------------
__global__ __launch_bounds__(256) void attn_kernel(
    const bf16* __restrict__ qkv, bf16* __restrict__ o)
{
    const int gw = blockIdx.x * 4 + (threadIdx.x >> 6);
    const int lane = threadIdx.x & 63;
    const int q = gw & (SS - 1);
    const int h = (gw >> 11) & (HH - 1);
    const int b = gw >> 15;
    const size_t rowstride = 3 * DD;
    const bf16* base = qkv + (size_t)b * SS * rowstride + h * HDD + lane;
    float qd = (float)base[(size_t)q * rowstride] * 0.125f;  // 1/sqrt(64)
    float kv[WW], vv[WW];
#pragma unroll
    for (int j = 0; j < WW; j++) {
        int key = q - (WW - 1) + j;
        int kc = key < 0 ? 0 : key;
        const bf16* kp = base + (size_t)kc * rowstride + DD;
        kv[j] = (float)kp[0];
        vv[j] = (float)kp[DD];
    }
    float sc[WW];
#pragma unroll
    for (int j = 0; j < WW; j++) {
        float p = qd * kv[j];
        p += __shfl_xor(p, 32, 64);
        p += __shfl_xor(p, 16, 64);
        p += __shfl_xor(p,  8, 64);
        p += __shfl_xor(p,  4, 64);
        p += __shfl_xor(p,  2, 64);
        p += __shfl_xor(p,  1, 64);
        sc[j] = (q - (WW - 1) + j >= 0) ? p : -1e30f;
    }
    float m = sc[0];
#pragma unroll
    for (int j = 1; j < WW; j++) m = fmaxf(m, sc[j]);
    float l = 0.f, od = 0.f;
#pragma unroll
    for (int j = 0; j < WW; j++) {
        float e = __expf(sc[j] - m);
        l += e;
        od += e * vv[j];
    }
    o[(size_t)(b * SS + q) * DD + h * HDD + lane] = (bf16)(od / l);
}

// ---------------- launch ----------------
extern "C" void kernel_launch(void* const* d_in, const int* in_sizes, int n_in,
                              void* d_out, int out_size, void* d_ws, size_t ws_size,
                              hipStream_t stream)
{
    (void)in_sizes; (void)n_in; (void)out_size; (void)ws_size;
    const float* x    = (const float*)d_in[0];
    const float* ln1g = (const float*)d_in[1];
    const float* ln1b = (const float*)d_in[2];
    const float* Wqkv = (const float*)d_in[3];
    const float* bqkv = (const float*)d_in[4];
    const float* Wout = (const float*)d_in[5];
    const float* bout = (const float*)d_in[6];
    const float* ln2g = (const float*)d_in[7];
    const float* ln2b = (const float*)d_in[8];
    const float* W1   = (const float*)d_in[9];
    const float* b1   = (const float*)d_in[10];
    const float* W2   = (const float*)d_in[11];
    const float* b2   = (const float*)d_in[12];

    // Workspace (56 MiB peak):
    //   [0,16M)  W region. Phase A: Wqkv_bf @0..6M, Wout_bf @6..8M.
    //            Phase B: W1_bf @0..8M, W2_bf @8..16M (conv after out-proj).
    //   [16,48M) P region. Phase A: qkv bf16 24 MiB. Phase B: h1 bf16 32 MiB.
    //   [48,56M) H region: h (LN1 out) -> o (attn out) -> xn (LN2 out), serially.
    //   x1 fp32 lives in d_out; MLP2 split-K atomically accumulates in place
    //   (x1 already holds the residual written by the out-proj GEMM).
    const size_t MB = (size_t)1 << 20;
    char* ws = (char*)d_ws;
    bf16* wqkv_bf = (bf16*)(ws);
    bf16* wout_bf = (bf16*)(ws + 6 * MB);
    bf16* w1_bf   = (bf16*)(ws);
    bf16* w2_bf   = (bf16*)(ws + 8 * MB);
    bf16* qkv     = (bf16*)(ws + 16 * MB);
    bf16* h1      = (bf16*)(ws + 16 * MB);
    bf16* hbuf    = (bf16*)(ws + 48 * MB);   // h, then o, then xn
    float* x1     = (float*)d_out;

    const dim3 blk(256);

    // Phase A: weights for QKV + out-proj
    conv_kernel<<<(3 * DD * DD / 8) / 256, blk, 0, stream>>>(Wqkv, wqkv_bf, 3 * DD * DD / 8);
    conv_kernel<<<(DD * DD / 8) / 256, blk, 0, stream>>>(Wout, wout_bf, DD * DD / 8);
    // h = LN1(x)
    ln_kernel<<<NTOK, blk, 0, stream>>>(x, ln1g, ln1b, hbuf);
    // qkv = h @ Wqkv^T + bqkv           (M=4096, N=3072, K=1024)
    gemm_glds<128, 0, 0, 0><<<dim3(24, 32), blk, 0, stream>>>(
        hbuf, wqkv_bf, bqkv, nullptr, qkv, 3 * DD, DD);
    // o = attention(qkv)  (o overwrites h — h dead)
    attn_kernel<<<BB * HH * SS / 4, blk, 0, stream>>>(qkv, hbuf);
    // x1 = x + o @ Wout^T + bout        (fp32 into d_out; M=4096, N=1024, K=1024)
    gemm_glds<64, 0, 2, 1><<<dim3(8, 64), blk, 0, stream>>>(
        hbuf, wout_bf, bout, x, x1, DD, DD);

    // Phase B: weights for MLP (overwrites phase-A weights; stream-ordered after out-proj)
    conv_kernel<<<(DFFD * DD / 8) / 256, blk, 0, stream>>>(W1, w1_bf, DFFD * DD / 8);
    conv_kernel<<<(DFFD * DD / 8) / 256, blk, 0, stream>>>(W2, w2_bf, DFFD * DD / 8);
    // xn = LN2(x1)   (xn overwrites o — o dead)
    ln_kernel<<<NTOK, blk, 0, stream>>>(x1, ln2g, ln2b, hbuf);
    // h1 = gelu(xn @ W1^T + b1)         (M=4096, N=4096, K=1024; h1 overwrites qkv)
    gemm_glds<128, 1, 0, 0><<<dim3(32, 32), blk, 0, stream>>>(
        hbuf, w1_bf, b1, nullptr, h1, DFFD, DD);
    // out = x1 + h1 @ W2^T + b2         (split-K=2, TM=128: grid 512 blocks = 2/CU;
    //   atomics accumulate into pre-primed x1 in d_out)
    gemm_glds<128, 0, 3, 1><<<dim3(8, 32, 2), blk, 0, stream>>>(
        h1, w2_bf, b2, nullptr, x1, DD, DFFD);
}

// Round 3
// 316.300 us; speedup vs baseline: 1.2961x; 1.1682x over previous
//
#include <hip/hip_runtime.h>
#include <hip/hip_bf16.h>
#include <cmath>

typedef __bf16 bf16;
typedef __bf16 bf16x4 __attribute__((ext_vector_type(4)));
typedef __bf16 bf16x8 __attribute__((ext_vector_type(8)));
typedef float f32x4 __attribute__((ext_vector_type(4)));

#define BB 2
#define SS 2048
#define DD 1024
#define HH 16
#define WW 16
#define HDD 64
#define DFFD 4096
#define NTOK (BB*SS)

// gelu(x) = 0.5x(1+tanh(c(x+0.044715x^3))) = x*sigmoid(2c(x+0.044715x^3))
__device__ __forceinline__ float gelu_f(float x) {
    const float k = 1.5957691216057308f;  // 2*sqrt(2/pi)
    float u = k * (x + 0.044715f * x * x * x);
    return x / (1.0f + __expf(-u));
}

// ---- async global->LDS 16B/lane. LDS dest = wave-uniform base + lane*16 (m104/m108). ----
__device__ __forceinline__ void glds16(const bf16* g, const bf16* l) {
    __builtin_amdgcn_global_load_lds(
        (const __attribute__((address_space(1))) void*)(uintptr_t)(const void*)g,
        (__attribute__((address_space(3))) void*)(unsigned)(uintptr_t)(const void*)l,
        16, 0, 0);
}

// ---------------- fp32 -> bf16 convert, 8 elems/thread ----------------
__global__ __launch_bounds__(256) void conv_kernel(
    const float* __restrict__ src, bf16* __restrict__ dst, int n8)
{
    int i = blockIdx.x * 256 + threadIdx.x;
    if (i >= n8) return;
    f32x4 a = *(const f32x4*)(src + (size_t)i * 8);
    f32x4 b = *(const f32x4*)(src + (size_t)i * 8 + 4);
    bf16x8 v;
#pragma unroll
    for (int j = 0; j < 4; j++) { v[j] = (bf16)a[j]; v[4 + j] = (bf16)b[j]; }
    *(bf16x8*)(dst + (size_t)i * 8) = v;
}

// ---------------- fused LayerNorm: fp32 row -> bf16 row, one block/row ----------------
__global__ __launch_bounds__(256) void ln_kernel(
    const float* __restrict__ x, const float* __restrict__ g, const float* __restrict__ b,
    bf16* __restrict__ out)
{
    const int row = blockIdx.x, t = threadIdx.x;
    f32x4 v = *(const f32x4*)(x + (size_t)row * DD + t * 4);
    float s  = v[0] + v[1] + v[2] + v[3];
    float s2 = v[0]*v[0] + v[1]*v[1] + v[2]*v[2] + v[3]*v[3];
#pragma unroll
    for (int off = 32; off >= 1; off >>= 1) {
        s  += __shfl_xor(s,  off, 64);
        s2 += __shfl_xor(s2, off, 64);
    }
    __shared__ float red[8];
    const int wave = t >> 6;
    if ((t & 63) == 0) { red[wave] = s; red[4 + wave] = s2; }
    __syncthreads();
    float ts  = red[0] + red[1] + red[2] + red[3];
    float ts2 = red[4] + red[5] + red[6] + red[7];
    float mean = ts * (1.0f / DD);
    float var  = ts2 * (1.0f / DD) - mean * mean;
    float rstd = rsqrtf(var + 1e-5f);
    f32x4 gv = *(const f32x4*)(g + t * 4);
    f32x4 bv = *(const f32x4*)(b + t * 4);
    bf16x4 o;
#pragma unroll
    for (int i = 0; i < 4; i++) o[i] = (bf16)((v[i] - mean) * rstd * gv[i] + bv[i]);
    *(bf16x4*)(out + (size_t)row * DD + t * 4) = o;
}

// ---------------- bf16 MFMA GEMM, 2-phase double-buffered glds prefetch ----------------
// C[M,N] = A[M,K] @ W[N,K]^T + bias. (T3-minimum-2phase, m228d.)
template<int TM, int ACT, int RESID, int OUTF32>
__global__ __launch_bounds__(256) void gemm_glds(
    const bf16* __restrict__ A, const bf16* __restrict__ Bw,
    const float* __restrict__ bias,
    const float* resid, void* __restrict__ Cout, int N, int K)
{
    constexpr int MI = 4;
    constexpr int NJ = (TM == 128) ? 4 : 2;
    __shared__ __align__(16) bf16 As[2 * TM * 32];
    __shared__ __align__(16) bf16 Bs[2 * 128 * 32];
    const int t = threadIdx.x;
    const int m0 = blockIdx.y * TM, n0 = blockIdx.x * 128;
    const int lane = t & 63, w = t >> 6;
    const int wm = (TM == 128) ? (w & 1) * 64 : 0;
    const int wn = (TM == 128) ? (w >> 1) * 64 : w * 32;
    const int quad = lane >> 4, l16 = lane & 15;
    const int srow = t >> 2, scol = (t & 3) * 8;   // 4 lanes/row, 8 bf16 (16 B) each

    const bf16* Ag = A  + (size_t)(m0 + srow) * K + scol;
    const bf16* Bg = Bw + (size_t)(n0 + srow) * K + scol;

    int k_lo = 0, k_hi = K;
    if (RESID == 3) {                 // split-K: this block handles one K-slice
        const int ks = K / gridDim.z;
        k_lo = blockIdx.z * ks;
        k_hi = k_lo + ks;
    }

    auto stage = [&](int buf, int k0) {
        const bf16* AsW = As + buf * (TM * 32) + w * 512;
        const bf16* BsW = Bs + buf * (128 * 32) + w * 512;
        glds16(Ag + k0, AsW);
        if (TM == 128) glds16(Ag + (size_t)64 * K + k0, AsW + 2048);
        glds16(Bg + k0, BsW);
        glds16(Bg + (size_t)64 * K + k0, BsW + 2048);
    };

    const f32x4 zero = {0.f, 0.f, 0.f, 0.f};
    f32x4 acc[MI][NJ];
#pragma unroll
    for (int i = 0; i < MI; i++)
#pragma unroll
        for (int j = 0; j < NJ; j++) acc[i][j] = zero;

    const int nsteps = (k_hi - k_lo) >> 5;
    stage(0, k_lo);
    __syncthreads();                           // drains vmcnt -> buf0 visible

    for (int step = 0; step < nsteps; ++step) {
        const int cur = step & 1;
        if (step + 1 < nsteps)
            stage(cur ^ 1, k_lo + ((step + 1) << 5));   // prefetch next tile
        const bf16* Ab = As + cur * (TM * 32);
        const bf16* Bb = Bs + cur * (128 * 32);
        bf16x8 af[MI], bfr[NJ];
#pragma unroll
        for (int i = 0; i < MI; i++)
            af[i] = *(const bf16x8*)(Ab + (wm + i * 16 + l16) * 32 + quad * 8);
#pragma unroll
        for (int j = 0; j < NJ; j++)
            bfr[j] = *(const bf16x8*)(Bb + (wn + j * 16 + l16) * 32 + quad * 8);
#pragma unroll
        for (int i = 0; i < MI; i++)
#pragma unroll
            for (int j = 0; j < NJ; j++)
                acc[i][j] = __builtin_amdgcn_mfma_f32_16x16x32_bf16(af[i], bfr[j], acc[i][j], 0, 0, 0);
        __syncthreads();   // implicit vmcnt(0)+lgkmcnt(0): prefetch landed, reads done
    }

#pragma unroll
    for (int i = 0; i < MI; i++) {
#pragma unroll
        for (int j = 0; j < NJ; j++) {
            int col = n0 + wn + j * 16 + l16;
            float bv = bias[col];
            if (RESID == 3 && blockIdx.z != 0) bv = 0.0f;
#pragma unroll
            for (int r = 0; r < 4; r++) {
                int row = m0 + wm + i * 16 + quad * 4 + r;
                float val = acc[i][j][r] + bv;
                if (ACT == 1) val = gelu_f(val);
                size_t idx = (size_t)row * N + col;
                if (RESID == 2) val += resid[idx];
                if (RESID == 3) {
                    unsafeAtomicAdd(&((float*)Cout)[idx], val);   // HW global_atomic_add_f32
                } else if (OUTF32) {
                    ((float*)Cout)[idx] = val;
                } else {
                    ((bf16*)Cout)[idx] = (bf16)val;
                }
            }
        }
    }
}

// ---------------- Sliding-window causal attention, MFMA-tiled ----------------
// One wave per (b, h, 16-query block). Window W=16 -> keys span 31 rows = two
// 16-key tiles: KT0 = keys q0-16..q0-1, KT1 = keys q0..q0+15.
// QK^T: 4 MFMAs (A/B frags read DIRECT from global in row-major [16][k] layout —
// same fragment pattern as gemm_glds, proven m89/m91).
// Mask (C-layout: row=q=quad*4+r, col=key=l16): KT1 valid iff col<=row; KT0 valid
// iff col>row && key>=0. Masked -> -1e30 BEFORE max (garbage from clamped OOB rows
// never survives; P=0 kills garbage V in PV).
// Softmax: per row, butterfly over the 16-lane group (xor 1,2,4,8) — 8 shuffles/row.
// P: C-layout -> A-layout via 1KB wave-private LDS. V: 32 rows staged per-wave via
// glds16 (linear), consumed transposed by scalar ds_read_u16 B-frags. PV: 4 MFMAs.
// No __syncthreads (all LDS wave-private); one s_waitcnt vmcnt(0) covers V staging.
__global__ __launch_bounds__(256) void attn_kernel(
    const bf16* __restrict__ qkv, bf16* __restrict__ o)
{
    __shared__ __align__(16) bf16 Vlds[4][32 * 64];   // 16 KB: per-wave V tile
    __shared__ __align__(16) bf16 Plds[4][16 * 32];   //  4 KB: per-wave P transpose
    const int t = threadIdx.x;
    const int w = t >> 6, lane = t & 63;
    const int quad = lane >> 4, l16 = lane & 15;
    const int gw = blockIdx.x * 4 + w;
    const int qb = gw & 127;            // SS/16 = 128 query blocks per (b,h)
    const int h  = (gw >> 7) & (HH - 1);
    const int b  = gw >> 11;
    const int q0 = qb << 4;
    const size_t rs = 3 * DD;           // qkv row stride (elements)
    const bf16* Qb = qkv + (size_t)b * SS * rs + h * HDD;
    const bf16* Kb = Qb + DD;
    const bf16* Vb = Qb + 2 * DD;
    bf16* Vw = Vlds[w];
    bf16* Pw = Plds[w];

    // ---- stage V rows (keys q0-16 .. q0+15) into wave-private LDS, rows clamped >=0
    {
        const int sub = lane >> 3;          // row within 8-row chunk
        const int dc  = (lane & 7) * 8;     // 8 bf16 = 16 B per lane
#pragma unroll
        for (int c = 0; c < 4; c++) {
            int key = q0 - 16 + c * 8 + sub;
            if (key < 0) key = 0;
            glds16(Vb + (size_t)key * rs + dc, Vw + c * 512);
        }
    }

    // ---- Q / K fragments direct from global (row-major [16][k], 16B/lane)
    const int qrow = q0 + l16;
    int kr0 = q0 - 16 + l16; if (kr0 < 0) kr0 = 0;
    bf16x8 qf0  = *(const bf16x8*)(Qb + (size_t)qrow * rs + quad * 8);
    bf16x8 qf1  = *(const bf16x8*)(Qb + (size_t)qrow * rs + 32 + quad * 8);
    bf16x8 kf0a = *(const bf16x8*)(Kb + (size_t)kr0  * rs + quad * 8);
    bf16x8 kf0b = *(const bf16x8*)(Kb + (size_t)kr0  * rs + 32 + quad * 8);
    bf16x8 kf1a = *(const bf16x8*)(Kb + (size_t)qrow * rs + quad * 8);
    bf16x8 kf1b = *(const bf16x8*)(Kb + (size_t)qrow * rs + 32 + quad * 8);

    const f32x4 zero = {0.f, 0.f, 0.f, 0.f};
    f32x4 acc0 = __builtin_amdgcn_mfma_f32_16x16x32_bf16(qf0, kf0a, zero, 0, 0, 0);
    acc0 = __builtin_amdgcn_mfma_f32_16x16x32_bf16(qf1, kf0b, acc0, 0, 0, 0);
    f32x4 acc1 = __builtin_amdgcn_mfma_f32_16x16x32_bf16(qf0, kf1a, zero, 0, 0, 0);
    acc1 = __builtin_amdgcn_mfma_f32_16x16x32_bf16(qf1, kf1b, acc1, 0, 0, 0);

    // ---- mask + row softmax; write P (bf16, unnormalized) to LDS in A-layout order
    float rl[4];
#pragma unroll
    for (int r = 0; r < 4; r++) {
        const int row = quad * 4 + r;
        float s0 = (l16 > row && q0 - 16 + l16 >= 0) ? acc0[r] * 0.125f : -1e30f;
        float s1 = (l16 <= row)                      ? acc1[r] * 0.125f : -1e30f;
        float m = fmaxf(s0, s1);
        m = fmaxf(m, __shfl_xor(m, 1, 64));
        m = fmaxf(m, __shfl_xor(m, 2, 64));
        m = fmaxf(m, __shfl_xor(m, 4, 64));
        m = fmaxf(m, __shfl_xor(m, 8, 64));
        float e0 = __expf(s0 - m), e1 = __expf(s1 - m);
        float sum = e0 + e1;
        sum += __shfl_xor(sum, 1, 64);
        sum += __shfl_xor(sum, 2, 64);
        sum += __shfl_xor(sum, 4, 64);
        sum += __shfl_xor(sum, 8, 64);
        rl[r] = 1.0f / sum;
        Pw[row * 32 + l16]      = (bf16)e0;   // cols 0..15  = KT0 keys
        Pw[row * 32 + 16 + l16] = (bf16)e1;   // cols 16..31 = KT1 keys
    }

    // ---- P·V: A-frag from Plds (K=32), B-frag = V^T via scalar LDS reads
    asm volatile("s_waitcnt vmcnt(0)" ::: "memory");   // V staging landed
    bf16x8 pf = *(const bf16x8*)(Pw + l16 * 32 + quad * 8);
#pragma unroll
    for (int dt = 0; dt < 4; dt++) {
        bf16x8 vf;
#pragma unroll
        for (int jj = 0; jj < 8; jj++)
            vf[jj] = Vw[(quad * 8 + jj) * 64 + dt * 16 + l16];
        f32x4 ov = __builtin_amdgcn_mfma_f32_16x16x32_bf16(pf, vf, zero, 0, 0, 0);
#pragma unroll
        for (int r = 0; r < 4; r++) {
            const int row = quad * 4 + r;
            o[(size_t)(b * SS + q0 + row) * DD + h * HDD + dt * 16 + l16] =
                (bf16)(ov[r] * rl[r]);
        }
    }
}

// ---------------- launch ----------------
extern "C" void kernel_launch(void* const* d_in, const int* in_sizes, int n_in,
                              void* d_out, int out_size, void* d_ws, size_t ws_size,
                              hipStream_t stream)
{
    (void)in_sizes; (void)n_in; (void)out_size; (void)ws_size;
    const float* x    = (const float*)d_in[0];
    const float* ln1g = (const float*)d_in[1];
    const float* ln1b = (const float*)d_in[2];
    const float* Wqkv = (const float*)d_in[3];
    const float* bqkv = (const float*)d_in[4];
    const float* Wout = (const float*)d_in[5];
    const float* bout = (const float*)d_in[6];
    const float* ln2g = (const float*)d_in[7];
    const float* ln2b = (const float*)d_in[8];
    const float* W1   = (const float*)d_in[9];
    const float* b1   = (const float*)d_in[10];
    const float* W2   = (const float*)d_in[11];
    const float* b2   = (const float*)d_in[12];

    // Workspace (56 MiB peak):
    //   [0,16M)  W region. Phase A: Wqkv_bf @0..6M, Wout_bf @6..8M.
    //            Phase B: W1_bf @0..8M, W2_bf @8..16M (conv after out-proj).
    //   [16,48M) P region. Phase A: qkv bf16 24 MiB. Phase B: h1 bf16 32 MiB.
    //   [48,56M) H region: h (LN1 out) -> o (attn out) -> xn (LN2 out), serially.
    //   x1 fp32 lives in d_out; MLP2 split-K atomically accumulates in place.
    const size_t MB = (size_t)1 << 20;
    char* ws = (char*)d_ws;
    bf16* wqkv_bf = (bf16*)(ws);
    bf16* wout_bf = (bf16*)(ws + 6 * MB);
    bf16* w1_bf   = (bf16*)(ws);
    bf16* w2_bf   = (bf16*)(ws + 8 * MB);
    bf16* qkv     = (bf16*)(ws + 16 * MB);
    bf16* h1      = (bf16*)(ws + 16 * MB);
    bf16* hbuf    = (bf16*)(ws + 48 * MB);   // h, then o, then xn
    float* x1     = (float*)d_out;

    const dim3 blk(256);

    // Phase A: weights for QKV + out-proj
    conv_kernel<<<(3 * DD * DD / 8) / 256, blk, 0, stream>>>(Wqkv, wqkv_bf, 3 * DD * DD / 8);
    conv_kernel<<<(DD * DD / 8) / 256, blk, 0, stream>>>(Wout, wout_bf, DD * DD / 8);
    // h = LN1(x)
    ln_kernel<<<NTOK, blk, 0, stream>>>(x, ln1g, ln1b, hbuf);
    // qkv = h @ Wqkv^T + bqkv           (M=4096, N=3072, K=1024)
    gemm_glds<128, 0, 0, 0><<<dim3(24, 32), blk, 0, stream>>>(
        hbuf, wqkv_bf, bqkv, nullptr, qkv, 3 * DD, DD);
    // o = attention(qkv)  (o overwrites h — h dead). 4096 waves = 1024 blocks.
    attn_kernel<<<BB * HH * (SS / 16) / 4, blk, 0, stream>>>(qkv, hbuf);
    // x1 = x + o @ Wout^T + bout        (fp32 into d_out; M=4096, N=1024, K=1024)
    gemm_glds<64, 0, 2, 1><<<dim3(8, 64), blk, 0, stream>>>(
        hbuf, wout_bf, bout, x, x1, DD, DD);

    // Phase B: weights for MLP (overwrites phase-A weights; stream-ordered after out-proj)
    conv_kernel<<<(DFFD * DD / 8) / 256, blk, 0, stream>>>(W1, w1_bf, DFFD * DD / 8);
    conv_kernel<<<(DFFD * DD / 8) / 256, blk, 0, stream>>>(W2, w2_bf, DFFD * DD / 8);
    // xn = LN2(x1)   (xn overwrites o — o dead)
    ln_kernel<<<NTOK, blk, 0, stream>>>(x1, ln2g, ln2b, hbuf);
    // h1 = gelu(xn @ W1^T + b1)         (M=4096, N=4096, K=1024; h1 overwrites qkv)
    gemm_glds<128, 1, 0, 0><<<dim3(32, 32), blk, 0, stream>>>(
        hbuf, w1_bf, b1, nullptr, h1, DFFD, DD);
    // out = x1 + h1 @ W2^T + b2         (split-K=2, TM=128; atomics into pre-primed x1)
    gemm_glds<128, 0, 3, 1><<<dim3(8, 32, 2), blk, 0, stream>>>(
        h1, w2_bf, b2, nullptr, x1, DD, DFFD);
}